// Round 3
// baseline (2202.040 us; speedup 1.0000x reference)
//
#include <hip/hip_runtime.h>
#include <hip/hip_bf16.h>
#include <math.h>

#define D 128
#define NEG 0.2f
#define EPSV 1e-16f
#define NBLK 256
#define NTHR 1024
#define NPG 5          // nodes per 128-thread col-group in linear phase
#define NPB 40         // 8 groups * NPG nodes per block

// ---------------- device-scope grid barrier (generation-based) ----------------
// All 256 blocks are co-resident (grid == CU count, launch_bounds caps VGPR).
// Relaxed spin on LLC + single acquire fence on wake (avoid per-poll buffer_inv
// of the shared per-XCD L2).
__device__ __forceinline__ void gsync(unsigned* cnt, unsigned* gen){
  __syncthreads();
  if (threadIdx.x == 0){
    __threadfence();   // release: write-back this XCD's L2 to LLC
    unsigned g = __hip_atomic_load(gen, __ATOMIC_RELAXED, __HIP_MEMORY_SCOPE_AGENT);
    unsigned a = __hip_atomic_fetch_add(cnt, 1u, __ATOMIC_RELAXED, __HIP_MEMORY_SCOPE_AGENT);
    if (a == (unsigned)(gridDim.x - 1u)){
      __hip_atomic_store(cnt, 0u, __ATOMIC_RELAXED, __HIP_MEMORY_SCOPE_AGENT);
      __hip_atomic_store(gen, g + 1u, __ATOMIC_RELEASE, __HIP_MEMORY_SCOPE_AGENT);
    } else {
      while (__hip_atomic_load(gen, __ATOMIC_RELAXED, __HIP_MEMORY_SCOPE_AGENT) == g){
        __builtin_amdgcn_s_sleep(1);
      }
    }
    __threadfence();   // acquire: invalidate stale L1/L2 before reading peers' data
  }
  __syncthreads();
}

// ---------------- linear phase: h = x@W, es/ed attention dots ----------------
template<int HEADS>
__device__ void linear_phase(const float* __restrict__ x, const float* __restrict__ W,
                             const float* __restrict__ asrc, const float* __restrict__ adst,
                             int N, float* __restrict__ h, float* __restrict__ es, float* __restrict__ ed,
                             float* pE, float* pD){
  const int t   = threadIdx.x;
  const int col = t & (D-1);
  const int g   = t >> 7;                  // 0..7, wave-pair uniform
  const float av = asrc[col], bv = adst[col];
  const int stride = gridDim.x * NPB;
  for (int base = blockIdx.x * NPB; base < N; base += stride){
    const int n0 = base + g * NPG;
    int nsc[NPG];
    #pragma unroll
    for (int j=0;j<NPG;j++){
      int nj = n0 + j; if (nj > N-1) nj = N-1;
      nsc[j] = __builtin_amdgcn_readfirstlane(nj);   // force SGPR -> s_load path
    }
    float acc[NPG];
    #pragma unroll
    for (int j=0;j<NPG;j++) acc[j]=0.f;
    const float* wp = W + col;
    #pragma unroll 4
    for (int k4=0; k4<D/4; k4++){
      const float w0 = wp[(k4*4+0)*D];
      const float w1 = wp[(k4*4+1)*D];
      const float w2 = wp[(k4*4+2)*D];
      const float w3 = wp[(k4*4+3)*D];
      #pragma unroll
      for (int j=0;j<NPG;j++){
        const float4 xv = *reinterpret_cast<const float4*>(x + (size_t)nsc[j]*D + k4*4);
        acc[j] = fmaf(xv.w, w3, fmaf(xv.z, w2, fmaf(xv.y, w1, fmaf(xv.x, w0, acc[j]))));
      }
    }
    if constexpr (HEADS==4){
      #pragma unroll
      for (int j=0;j<NPG;j++){
        const int n = n0 + j;
        if (n < N){                                   // wave-uniform
          h[(size_t)n*D + col] = acc[j];
          float ps = acc[j]*av, pd = acc[j]*bv;
          #pragma unroll
          for (int off=16; off; off>>=1){ ps += __shfl_xor(ps, off, 32); pd += __shfl_xor(pd, off, 32); }
          if ((col&31)==0){ es[n*4 + (col>>5)] = ps; ed[n*4 + (col>>5)] = pd; }
        }
      }
    } else {
      const int wid = t >> 6;                         // 0..15
      #pragma unroll
      for (int j=0;j<NPG;j++){
        const int n = n0 + j;
        float ps = 0.f, pd = 0.f;
        if (n < N){
          h[(size_t)n*D + col] = acc[j];
          ps = acc[j]*av; pd = acc[j]*bv;
        }
        #pragma unroll
        for (int off=32; off; off>>=1){ ps += __shfl_xor(ps, off, 64); pd += __shfl_xor(pd, off, 64); }
        if ((t&63)==0){ pE[wid*NPG + j] = ps; pD[wid*NPG + j] = pd; }
      }
      __syncthreads();
      if (t < 8*NPG){
        const int g2 = t / NPG, j = t % NPG;
        const int n = base + g2*NPG + j;
        if (n < N){
          es[n] = pE[(2*g2)*NPG + j] + pE[(2*g2+1)*NPG + j];
          ed[n] = pD[(2*g2)*NPG + j] + pD[(2*g2+1)*NPG + j];
        }
      }
      __syncthreads();
    }
  }
}

// ---------------- aggregate phase: segment softmax + weighted sum ----------------
template<int HEADS, bool RELU>
__device__ void agg_phase(const float* __restrict__ h, const float* __restrict__ es, const float* __restrict__ ed,
                          const int* __restrict__ row_ptr, const int* __restrict__ csr_src,
                          const float* __restrict__ bias, float* __restrict__ out, int N){
  const int lane = threadIdx.x & 63;
  const int wid  = threadIdx.x >> 6;
  const int nwav = gridDim.x * (NTHR/64);
  const int c0   = lane*2;
  const int myh  = (HEADS==4) ? (lane>>4) : 0;
  const float bx = bias[c0], by = bias[c0+1];
  for (int n = blockIdx.x*(NTHR/64) + wid; n < N; n += nwav){
    const int start = row_ptr[n], end = row_ptr[n+1];
    const float edn = ed[n*HEADS + myh];
    float accx=0.f, accy=0.f, z=0.f;
    int e = start;
    for (; e+2 <= end; e+=2){
      const int s0 = csr_src[e], s1 = csr_src[e+1];
      float e0 = es[s0*HEADS+myh] + edn; e0 = (e0>=0.f)? e0 : NEG*e0; e0 = fminf(e0, 80.f);
      float e1 = es[s1*HEADS+myh] + edn; e1 = (e1>=0.f)? e1 : NEG*e1; e1 = fminf(e1, 80.f);
      const float p0 = __expf(e0), p1 = __expf(e1);
      const float2 h0 = *reinterpret_cast<const float2*>(h + (size_t)s0*D + c0);
      const float2 h1 = *reinterpret_cast<const float2*>(h + (size_t)s1*D + c0);
      z += p0 + p1;
      accx = fmaf(p0, h0.x, accx); accx = fmaf(p1, h1.x, accx);
      accy = fmaf(p0, h0.y, accy); accy = fmaf(p1, h1.y, accy);
    }
    if (e < end){
      const int s0 = csr_src[e];
      float e0 = es[s0*HEADS+myh] + edn; e0 = (e0>=0.f)? e0 : NEG*e0; e0 = fminf(e0, 80.f);
      const float p0 = __expf(e0);
      const float2 h0 = *reinterpret_cast<const float2*>(h + (size_t)s0*D + c0);
      z += p0;
      accx = fmaf(p0, h0.x, accx);
      accy = fmaf(p0, h0.y, accy);
    }
    const float inv = 1.f/(z + EPSV);
    float ox = fmaf(accx, inv, bx), oy = fmaf(accy, inv, by);
    if (RELU){ ox = fmaxf(ox,0.f); oy = fmaxf(oy,0.f); }
    *reinterpret_cast<float2*>(out + (size_t)n*D + c0) = make_float2(ox, oy);
  }
}

// ---------------- the whole network in one kernel ----------------
__global__ __launch_bounds__(NTHR, 4)
void gat_uber(const float* __restrict__ x, const int* __restrict__ esrc, const int* __restrict__ edst,
              const float* __restrict__ Ws, const float* __restrict__ a_src, const float* __restrict__ a_dst,
              const float* __restrict__ bs, const float* __restrict__ W_last,
              const float* __restrict__ a_src_last, const float* __restrict__ a_dst_last,
              const float* __restrict__ b_last,
              int N, int E, int L,
              float* h, float* xb0, float* xb1, float* es, float* ed,
              int* deg, int* row_ptr, int* cursor, int* csr_src,
              unsigned* bar, float* out){
  __shared__ int part[1024];
  __shared__ float pE[16*NPG], pD[16*NPG];
  unsigned* cnt = bar;
  unsigned* gen = bar + 1;
  const int t = threadIdx.x;
  const int gid = blockIdx.x*NTHR + t;
  const int gstride = gridDim.x*NTHR;
  const int tot = E + N;

  // --- CSR build ---
  for (int i = gid; i < N; i += gstride) deg[i] = 0;
  gsync(cnt, gen);
  for (int i = gid; i < tot; i += gstride){
    const int d2 = (i < E) ? edst[i] : (i - E);
    atomicAdd(&deg[d2], 1);
  }
  gsync(cnt, gen);
  if (blockIdx.x == 0){
    const int CH = 16;                 // 1024*16 = 16384 >= N
    const int base2 = t*CH;
    int local[CH]; int s = 0;
    #pragma unroll
    for (int j=0;j<CH;j++){ const int idx=base2+j; const int v=(idx<N)? deg[idx]:0; local[j]=s; s+=v; }
    part[t]=s; __syncthreads();
    for (int off=1; off<1024; off<<=1){
      const int v = (t>=off)? part[t-off] : 0;
      __syncthreads();
      part[t]+=v;
      __syncthreads();
    }
    const int cb = (t==0)? 0 : part[t-1];
    #pragma unroll
    for (int j=0;j<CH;j++){ const int idx=base2+j; if(idx<N){ const int r=cb+local[j]; row_ptr[idx]=r; cursor[idx]=r; } }
    if (t==1023) row_ptr[N]=part[1023];
  }
  gsync(cnt, gen);
  for (int i = gid; i < tot; i += gstride){
    int s2, d2;
    if (i < E){ s2=esrc[i]; d2=edst[i]; } else { s2=i-E; d2=i-E; }
    const int pos = atomicAdd(&cursor[d2], 1);
    csr_src[pos] = s2;
  }
  gsync(cnt, gen);

  // --- 19 mid layers ---
  const float* xin = x;
  for (int l=0; l<L; l++){
    linear_phase<4>(xin, Ws + (size_t)l*D*D, a_src + (size_t)l*D, a_dst + (size_t)l*D,
                    N, h, es, ed, pE, pD);
    gsync(cnt, gen);
    float* xout = (l & 1) ? xb1 : xb0;
    agg_phase<4,true>(h, es, ed, row_ptr, csr_src, bs + (size_t)l*D, xout, N);
    gsync(cnt, gen);
    xin = xout;
  }
  // --- last layer (heads=1, no relu) ---
  linear_phase<1>(xin, W_last, a_src_last, a_dst_last, N, h, es, ed, pE, pD);
  gsync(cnt, gen);
  agg_phase<1,false>(h, es, ed, row_ptr, csr_src, b_last, out, N);
}

extern "C" void kernel_launch(void* const* d_in, const int* in_sizes, int n_in,
                              void* d_out, int out_size, void* d_ws, size_t ws_size,
                              hipStream_t stream) {
  const float* x          = (const float*)d_in[0];
  const int*   ei         = (const int*)d_in[1];
  const float* Ws         = (const float*)d_in[2];
  const float* a_src      = (const float*)d_in[3];
  const float* a_dst      = (const float*)d_in[4];
  const float* bs         = (const float*)d_in[5];
  const float* W_last     = (const float*)d_in[6];
  const float* a_src_last = (const float*)d_in[7];
  const float* a_dst_last = (const float*)d_in[8];
  const float* b_last     = (const float*)d_in[9];

  const int N = in_sizes[0]/D;
  const int E = in_sizes[1]/2;
  const int L = in_sizes[2]/(D*D);
  const int* esrc = ei;
  const int* edst = ei + E;

  // workspace layout
  char* ws = (char*)d_ws;
  float* h   = (float*)ws;  ws += (size_t)N*D*sizeof(float);
  float* xb0 = (float*)ws;  ws += (size_t)N*D*sizeof(float);
  float* xb1 = (float*)ws;  ws += (size_t)N*D*sizeof(float);
  float* es  = (float*)ws;  ws += (size_t)N*4*sizeof(float);
  float* ed  = (float*)ws;  ws += (size_t)N*4*sizeof(float);
  int* deg     = (int*)ws;  ws += (size_t)N*sizeof(int);
  int* row_ptr = (int*)ws;  ws += (size_t)(N+1)*sizeof(int);
  int* cursor  = (int*)ws;  ws += (size_t)N*sizeof(int);
  int* csr_src = (int*)ws;  ws += (size_t)(E+N)*sizeof(int);
  unsigned* bar = (unsigned*)ws; ws += 2*sizeof(unsigned);

  // barrier state must start at 0 every call (ws is poisoned 0xAA before timing)
  hipMemsetAsync(bar, 0, 2*sizeof(unsigned), stream);

  gat_uber<<<NBLK, NTHR, 0, stream>>>(x, esrc, edst, Ws, a_src, a_dst, bs,
                                      W_last, a_src_last, a_dst_last, b_last,
                                      N, E, L,
                                      h, xb0, xb1, es, ed,
                                      deg, row_ptr, cursor, csr_src,
                                      bar, (float*)d_out);
}

// Round 4
// 777.468 us; speedup vs baseline: 2.8323x; 2.8323x over previous
//
#include <hip/hip_runtime.h>
#include <hip/hip_bf16.h>
#include <math.h>

#define D 128
#define NEG 0.2f
#define EPSV 1e-16f

#define LIN_GROUPS 4
#define LIN_NPG 10
#define LIN_NPB (LIN_GROUPS*LIN_NPG)   // 40 nodes per 512-thread block

// ---------------- CSR build (once per call; graph constant across layers) ----------------
__global__ void count_kernel(const int* __restrict__ edst, int E, int N, int* __restrict__ deg){
  int i = blockIdx.x*blockDim.x + threadIdx.x;
  int tot = E + N;
  if (i >= tot) return;
  int d = (i < E) ? edst[i] : (i - E);
  atomicAdd(&deg[d], 1);
}

__global__ void scan_kernel(const int* __restrict__ deg, int N, int* __restrict__ row_ptr, int* __restrict__ cursor){
  __shared__ int part[1024];
  const int CH = 16;                 // 1024*16 = 16384 >= N
  int t = threadIdx.x;
  int base = t*CH;
  int local[CH]; int s = 0;
  #pragma unroll
  for (int j=0;j<CH;j++){ int idx=base+j; int v = (idx<N)? deg[idx] : 0; local[j]=s; s+=v; }
  part[t]=s; __syncthreads();
  for (int off=1; off<1024; off<<=1){
    int v = (t>=off)? part[t-off] : 0;
    __syncthreads();
    part[t]+=v;
    __syncthreads();
  }
  int cb = (t==0)? 0 : part[t-1];
  #pragma unroll
  for (int j=0;j<CH;j++){ int idx=base+j; if(idx<N){ int r=cb+local[j]; row_ptr[idx]=r; cursor[idx]=r; } }
  if (t==1023) row_ptr[N]=part[1023];
}

__global__ void scatter_kernel(const int* __restrict__ esrc, const int* __restrict__ edst,
                               int E, int N, int* __restrict__ cursor, int* __restrict__ csr_src){
  int i = blockIdx.x*blockDim.x + threadIdx.x;
  int tot = E + N;
  if (i>=tot) return;
  int s, d2;
  if (i<E){ s=esrc[i]; d2=edst[i]; } else { s=i-E; d2=i-E; }
  int pos = atomicAdd(&cursor[d2],1);
  csr_src[pos]=s;
}

// ---------------- Per-layer linear: h = x@W, es/ed attention dots ----------------
// 512 threads = 4 groups of 128 cols; each group computes LIN_NPG nodes.
// x rows are group-uniform -> readfirstlane'd pointers -> scalar (s_load) path;
// per k: ONE coalesced w-load (512B/wave) feeding LIN_NPG FMAs.
template<int HEADS>
__launch_bounds__(512, 2)
__global__ void linear_kernel(const float* __restrict__ x, const float* __restrict__ W,
                              const float* __restrict__ asrc, const float* __restrict__ adst,
                              int N, float* __restrict__ h, float* __restrict__ es, float* __restrict__ ed){
  const int t   = threadIdx.x;
  const int col = t & (D-1);
  const int g   = t >> 7;                      // 0..3, group id (128 threads each)
  const float av = asrc[col], bv = adst[col];
  const int n0 = blockIdx.x*LIN_NPB + g*LIN_NPG;

  const float* __restrict__ xr[LIN_NPG];
  #pragma unroll
  for (int j=0;j<LIN_NPG;j++){
    int nj = n0 + j; if (nj > N-1) nj = N-1;
    xr[j] = x + (size_t)__builtin_amdgcn_readfirstlane(nj) * D;
  }
  float acc[LIN_NPG];
  #pragma unroll
  for (int j=0;j<LIN_NPG;j++) acc[j]=0.f;

  #pragma unroll 8
  for (int k=0;k<D;k++){
    const float wv = W[(size_t)k*D + col];
    #pragma unroll
    for (int j=0;j<LIN_NPG;j++) acc[j] = fmaf(xr[j][k], wv, acc[j]);
  }

  if constexpr (HEADS==4){
    #pragma unroll
    for (int j=0;j<LIN_NPG;j++){
      const int n = n0 + j;
      if (n < N){                               // group-uniform branch
        h[(size_t)n*D + col] = acc[j];
        float ps = acc[j]*av, pd = acc[j]*bv;
        #pragma unroll
        for (int off=16; off; off>>=1){ ps += __shfl_xor(ps, off, 32); pd += __shfl_xor(pd, off, 32); }
        if ((col&31)==0){ es[n*4 + (col>>5)] = ps; ed[n*4 + (col>>5)] = pd; }
      }
    }
  } else {
    __shared__ float pE[LIN_GROUPS][2][LIN_NPG], pD[LIN_GROUPS][2][LIN_NPG];
    const int half = (t>>6)&1;                  // which wave within the group
    #pragma unroll
    for (int j=0;j<LIN_NPG;j++){
      const int n = n0 + j;
      float ps = 0.f, pd = 0.f;
      if (n < N){
        h[(size_t)n*D + col] = acc[j];
        ps = acc[j]*av; pd = acc[j]*bv;
      }
      #pragma unroll
      for (int off=32; off; off>>=1){ ps += __shfl_xor(ps, off, 64); pd += __shfl_xor(pd, off, 64); }
      if ((t&63)==0){ pE[g][half][j]=ps; pD[g][half][j]=pd; }
    }
    __syncthreads();
    if (t < LIN_NPB){
      const int g2 = t / LIN_NPG, j = t % LIN_NPG;
      const int n = blockIdx.x*LIN_NPB + t;
      if (n < N){
        es[n] = pE[g2][0][j] + pE[g2][1][j];
        ed[n] = pD[g2][0][j] + pD[g2][1][j];
      }
    }
  }
}

// ---------------- Per-layer aggregation: segment softmax + weighted sum ----------------
// One wave per dst node. Per 64-edge tile:
//   phase A (edge-parallel): gather csr_src + es, compute exp(lrelu(.)) for all heads -> wave-private LDS
//   phase B (channel-parallel): per edge, LDS broadcasts + INDEPENDENT h-row loads (unroll 4 -> pipelined)
// Single-pass softmax (no max subtraction; e is O(1), exp clamped at 80). No block barriers.
template<int HEADS, bool RELU>
__launch_bounds__(512, 8)
__global__ void aggregate_kernel(const float* __restrict__ h, const float* __restrict__ es, const float* __restrict__ ed,
                                 const int* __restrict__ row_ptr, const int* __restrict__ csr_src,
                                 const float* __restrict__ bias, float* __restrict__ out, int N){
  __shared__ int   sIdx[8][64];
  __shared__ float sP[8][64][HEADS];
  const int lane = threadIdx.x & 63;
  const int wid  = threadIdx.x >> 6;
  const int n = blockIdx.x*8 + wid;
  if (n >= N) return;
  const int start = row_ptr[n], end = row_ptr[n+1];
  const int myh = (HEADS==4) ? (lane>>4) : 0;

  float ed4[HEADS];
  #pragma unroll
  for (int hh=0;hh<HEADS;hh++) ed4[hh] = ed[n*HEADS + hh];

  const int c0 = lane*2;
  float accx=0.f, accy=0.f, z=0.f;

  for (int t0 = start; t0 < end; t0 += 64){
    const int cnt = min(64, end - t0);
    if (lane < cnt){
      const int s = csr_src[t0 + lane];
      sIdx[wid][lane] = s;
      if constexpr (HEADS==4){
        const float4 e4 = *reinterpret_cast<const float4*>(es + (size_t)s*4);
        float p0 = e4.x + ed4[0]; p0 = (p0>=0.f)? p0 : NEG*p0; p0 = fminf(p0, 80.f);
        float p1 = e4.y + ed4[1]; p1 = (p1>=0.f)? p1 : NEG*p1; p1 = fminf(p1, 80.f);
        float p2 = e4.z + ed4[2]; p2 = (p2>=0.f)? p2 : NEG*p2; p2 = fminf(p2, 80.f);
        float p3 = e4.w + ed4[3]; p3 = (p3>=0.f)? p3 : NEG*p3; p3 = fminf(p3, 80.f);
        sP[wid][lane][0] = __expf(p0);
        sP[wid][lane][1] = __expf(p1);
        sP[wid][lane][2] = __expf(p2);
        sP[wid][lane][3] = __expf(p3);
      } else {
        float p0 = es[s] + ed4[0]; p0 = (p0>=0.f)? p0 : NEG*p0; p0 = fminf(p0, 80.f);
        sP[wid][lane][0] = __expf(p0);
      }
    }
    // wave-private LDS: ds_write -> ds_read ordered by lgkmcnt within the wave; no barrier.
    #pragma unroll 4
    for (int e = 0; e < cnt; e++){
      const int s = sIdx[wid][e];
      const float p = sP[wid][e][myh];
      const float2 hv = *reinterpret_cast<const float2*>(h + (size_t)s*D + c0);
      z += p;
      accx = fmaf(p, hv.x, accx);
      accy = fmaf(p, hv.y, accy);
    }
  }
  const float inv = 1.f/(z + EPSV);
  float ox = fmaf(accx, inv, bias[c0]), oy = fmaf(accy, inv, bias[c0+1]);
  if (RELU){ ox = fmaxf(ox,0.f); oy = fmaxf(oy,0.f); }
  *reinterpret_cast<float2*>(out + (size_t)n*D + c0) = make_float2(ox, oy);
}

extern "C" void kernel_launch(void* const* d_in, const int* in_sizes, int n_in,
                              void* d_out, int out_size, void* d_ws, size_t ws_size,
                              hipStream_t stream) {
  const float* x          = (const float*)d_in[0];
  const int*   ei         = (const int*)d_in[1];
  const float* Ws         = (const float*)d_in[2];
  const float* a_src      = (const float*)d_in[3];
  const float* a_dst      = (const float*)d_in[4];
  const float* bs         = (const float*)d_in[5];
  const float* W_last     = (const float*)d_in[6];
  const float* a_src_last = (const float*)d_in[7];
  const float* a_dst_last = (const float*)d_in[8];
  const float* b_last     = (const float*)d_in[9];

  const int N = in_sizes[0]/D;
  const int E = in_sizes[1]/2;
  const int L = in_sizes[2]/(D*D);
  const int* esrc = ei;
  const int* edst = ei + E;

  // workspace layout
  char* ws = (char*)d_ws;
  float* h   = (float*)ws;  ws += (size_t)N*D*sizeof(float);
  float* xb0 = (float*)ws;  ws += (size_t)N*D*sizeof(float);
  float* xb1 = (float*)ws;  ws += (size_t)N*D*sizeof(float);
  float* es  = (float*)ws;  ws += (size_t)N*4*sizeof(float);
  float* ed  = (float*)ws;  ws += (size_t)N*4*sizeof(float);
  int* deg     = (int*)ws;  ws += (size_t)N*sizeof(int);
  int* row_ptr = (int*)ws;  ws += (size_t)(N+1)*sizeof(int);
  int* cursor  = (int*)ws;  ws += (size_t)N*sizeof(int);
  int* csr_src = (int*)ws;  ws += (size_t)(E+N)*sizeof(int);

  const int tot = E + N;
  hipMemsetAsync(deg, 0, (size_t)N*sizeof(int), stream);
  count_kernel<<<(tot+255)/256, 256, 0, stream>>>(edst, E, N, deg);
  scan_kernel<<<1, 1024, 0, stream>>>(deg, N, row_ptr, cursor);
  scatter_kernel<<<(tot+255)/256, 256, 0, stream>>>(esrc, edst, E, N, cursor, csr_src);

  const int gA = (N + LIN_NPB - 1)/LIN_NPB;   // 250 blocks
  const int gB = (N + 7)/8;                   // 1250 blocks

  const float* xin = x;
  for (int l=0; l<L; l++){
    linear_kernel<4><<<gA, 512, 0, stream>>>(xin, Ws + (size_t)l*D*D,
                                             a_src + (size_t)l*D, a_dst + (size_t)l*D,
                                             N, h, es, ed);
    float* xout = (l & 1) ? xb1 : xb0;
    aggregate_kernel<4,true><<<gB, 512, 0, stream>>>(h, es, ed, row_ptr, csr_src,
                                                     bs + (size_t)l*D, xout, N);
    xin = xout;
  }
  linear_kernel<1><<<gA, 512, 0, stream>>>(xin, W_last, a_src_last, a_dst_last, N, h, es, ed);
  aggregate_kernel<1,false><<<gB, 512, 0, stream>>>(h, es, ed, row_ptr, csr_src,
                                                    b_last, (float*)d_out, N);
}

// Round 5
// 573.091 us; speedup vs baseline: 3.8424x; 1.3566x over previous
//
#include <hip/hip_runtime.h>
#include <hip/hip_bf16.h>
#include <math.h>

#define D 128
#define NEG 0.2f
#define EPSV 1e-16f

// ---------------- CSR build (once per call; graph constant across layers) ----------------
__global__ void count_kernel(const int* __restrict__ edst, int E, int N, int* __restrict__ deg){
  int i = blockIdx.x*blockDim.x + threadIdx.x;
  int tot = E + N;
  if (i >= tot) return;
  int d = (i < E) ? edst[i] : (i - E);
  atomicAdd(&deg[d], 1);
}

__global__ void scan_kernel(const int* __restrict__ deg, int N, int* __restrict__ row_ptr, int* __restrict__ cursor){
  __shared__ int part[1024];
  const int CH = 16;                 // 1024*16 = 16384 >= N
  int t = threadIdx.x;
  int base = t*CH;
  int local[CH]; int s = 0;
  #pragma unroll
  for (int j=0;j<CH;j++){ int idx=base+j; int v = (idx<N)? deg[idx] : 0; local[j]=s; s+=v; }
  part[t]=s; __syncthreads();
  for (int off=1; off<1024; off<<=1){
    int v = (t>=off)? part[t-off] : 0;
    __syncthreads();
    part[t]+=v;
    __syncthreads();
  }
  int cb = (t==0)? 0 : part[t-1];
  #pragma unroll
  for (int j=0;j<CH;j++){ int idx=base+j; if(idx<N){ int r=cb+local[j]; row_ptr[idx]=r; cursor[idx]=r; } }
  if (t==1023) row_ptr[N]=part[1023];
}

__global__ void scatter_kernel(const int* __restrict__ esrc, const int* __restrict__ edst,
                               int E, int N, int* __restrict__ cursor, int* __restrict__ csr_src){
  int i = blockIdx.x*blockDim.x + threadIdx.x;
  int tot = E + N;
  if (i>=tot) return;
  int s, d2;
  if (i<E){ s=esrc[i]; d2=edst[i]; } else { s=i-E; d2=i-E; }
  int pos = atomicAdd(&cursor[d2],1);
  csr_src[pos]=s;
}

// ---------------- GEMV phase (shared by linear0 and fused kernels) ----------------
// Block = 512 threads = 4 col-groups of 128; rbuf holds 8 node rows in LDS
// (each group computes 2 nodes). Per k: 1 coalesced W load + 2 LDS broadcasts + 2 FMAs.
template<int HNEXT>
__device__ __forceinline__ void gemv_phase(const float (*rbuf)[D], int nbase, int N,
                                           const float* __restrict__ Wn,
                                           const float* __restrict__ av_, const float* __restrict__ bv_,
                                           float* __restrict__ h_out, float* __restrict__ es_out,
                                           float* __restrict__ ed_out, float* pE, float* pD){
  const int t   = threadIdx.x;
  const int col = t & (D-1);
  const int g   = t >> 7;                 // 0..3
  const float av = av_[col], bv = bv_[col];
  const float* __restrict__ r0 = rbuf[g*2+0];
  const float* __restrict__ r1 = rbuf[g*2+1];
  float a0=0.f, a1=0.f;
  #pragma unroll 4
  for (int k=0;k<D;k++){
    const float wv = Wn[(size_t)k*D + col];
    a0 = fmaf(r0[k], wv, a0);
    a1 = fmaf(r1[k], wv, a1);
  }
  if constexpr (HNEXT==4){
    #pragma unroll
    for (int j=0;j<2;j++){
      const float acc = j ? a1 : a0;
      const int n = nbase + g*2 + j;
      if (n < N){                          // group-uniform
        h_out[(size_t)n*D + col] = acc;
        float ps = acc*av, pd = acc*bv;
        #pragma unroll
        for (int off=16; off; off>>=1){ ps += __shfl_xor(ps, off, 32); pd += __shfl_xor(pd, off, 32); }
        if ((col&31)==0){ es_out[n*4 + (col>>5)] = ps; ed_out[n*4 + (col>>5)] = pd; }
      }
    }
  } else {
    const int half = (t>>6)&1;
    #pragma unroll
    for (int j=0;j<2;j++){
      const float acc = j ? a1 : a0;
      const int n = nbase + g*2 + j;
      float ps = 0.f, pd = 0.f;
      if (n < N){
        h_out[(size_t)n*D + col] = acc;
        ps = acc*av; pd = acc*bv;
      }
      #pragma unroll
      for (int off=32; off; off>>=1){ ps += __shfl_xor(ps, off, 64); pd += __shfl_xor(pd, off, 64); }
      if ((t&63)==0){ pE[(g*2+j)*2+half]=ps; pD[(g*2+j)*2+half]=pd; }
    }
    __syncthreads();
    if (t < 8){
      const int n = nbase + t;
      if (n < N){
        es_out[n] = pE[t*2+0]+pE[t*2+1];
        ed_out[n] = pD[t*2+0]+pD[t*2+1];
      }
    }
  }
}

// ---------------- Layer-0 linear: x rows -> LDS -> GEMV ----------------
__launch_bounds__(512, 8)
__global__ void linear0_kernel(const float* __restrict__ x, const float* __restrict__ Wn,
                               const float* __restrict__ an_src, const float* __restrict__ an_dst,
                               int N, float* __restrict__ h_out, float* __restrict__ es_out, float* __restrict__ ed_out){
  __shared__ float rbuf[8][D];
  __shared__ float pE[16], pD[16];
  const int t = threadIdx.x;
  const int nbase = blockIdx.x*8;
  {
    const int row = t >> 6;
    const int cc  = (t & 63)*2;
    int n = nbase + row; if (n > N-1) n = N-1;
    const float2 v = *reinterpret_cast<const float2*>(x + (size_t)n*D + cc);
    rbuf[row][cc] = v.x; rbuf[row][cc+1] = v.y;
  }
  __syncthreads();
  gemv_phase<4>(rbuf, nbase, N, Wn, an_src, an_dst, h_out, es_out, ed_out, pE, pD);
}

// ---------------- Fused: aggregate(layer l) + linear(layer l+1) ----------------
// Phase 1: one wave per dst node; per 64-edge tile gather csr+es, exp -> wave-private LDS,
// then channel-parallel accumulation (independent h-row loads, unroll 8). Softmax is
// single-pass (e is O(1); exp clamped at 80). Result row (bias+relu applied) -> rbuf.
// Phase 2: GEMV of the 8 aggregated rows with next layer's W + attention dots.
template<int HNEXT>
__launch_bounds__(512, 8)
__global__ void fused_kernel(const float* __restrict__ h, const float* __restrict__ es, const float* __restrict__ ed,
                             const int* __restrict__ row_ptr, const int* __restrict__ csr_src,
                             const float* __restrict__ bias,
                             const float* __restrict__ Wn, const float* __restrict__ an_src, const float* __restrict__ an_dst,
                             int N, float* __restrict__ h_out, float* __restrict__ es_out, float* __restrict__ ed_out){
  __shared__ int   sIdx[8][64];
  __shared__ float sP[8][64][4];
  __shared__ float rbuf[8][D];
  __shared__ float pE[16], pD[16];
  const int t = threadIdx.x;
  const int lane = t & 63;
  const int wid  = t >> 6;
  const int n = blockIdx.x*8 + wid;

  if (n < N){
    const int start = row_ptr[n], end = row_ptr[n+1];
    const int myh = lane>>4;
    float ed4[4];
    #pragma unroll
    for (int hh=0;hh<4;hh++) ed4[hh] = ed[n*4 + hh];
    const int c0 = lane*2;
    float accx=0.f, accy=0.f, z=0.f;
    for (int t0 = start; t0 < end; t0 += 64){
      const int cnt = min(64, end - t0);
      if (lane < cnt){
        const int s = csr_src[t0 + lane];
        sIdx[wid][lane] = s;
        const float4 e4 = *reinterpret_cast<const float4*>(es + (size_t)s*4);
        float p0 = e4.x + ed4[0]; p0 = (p0>=0.f)? p0 : NEG*p0; p0 = fminf(p0, 80.f);
        float p1 = e4.y + ed4[1]; p1 = (p1>=0.f)? p1 : NEG*p1; p1 = fminf(p1, 80.f);
        float p2 = e4.z + ed4[2]; p2 = (p2>=0.f)? p2 : NEG*p2; p2 = fminf(p2, 80.f);
        float p3 = e4.w + ed4[3]; p3 = (p3>=0.f)? p3 : NEG*p3; p3 = fminf(p3, 80.f);
        sP[wid][lane][0] = __expf(p0);
        sP[wid][lane][1] = __expf(p1);
        sP[wid][lane][2] = __expf(p2);
        sP[wid][lane][3] = __expf(p3);
      }
      #pragma unroll 8
      for (int e = 0; e < cnt; e++){
        const int s = sIdx[wid][e];
        const float p = sP[wid][e][myh];
        const float2 hv = *reinterpret_cast<const float2*>(h + (size_t)s*D + c0);
        z += p;
        accx = fmaf(p, hv.x, accx);
        accy = fmaf(p, hv.y, accy);
      }
    }
    const float inv = 1.f/(z + EPSV);
    float ox = fmaf(accx, inv, bias[c0]), oy = fmaf(accy, inv, bias[c0+1]);
    ox = fmaxf(ox, 0.f); oy = fmaxf(oy, 0.f);      // mid layers always relu
    rbuf[wid][c0] = ox; rbuf[wid][c0+1] = oy;
  }
  __syncthreads();
  gemv_phase<HNEXT>(rbuf, blockIdx.x*8, N, Wn, an_src, an_dst, h_out, es_out, ed_out, pE, pD);
}

// ---------------- Final aggregation (heads=1, no relu) -> d_out ----------------
__launch_bounds__(512, 8)
__global__ void final_agg_kernel(const float* __restrict__ h, const float* __restrict__ es, const float* __restrict__ ed,
                                 const int* __restrict__ row_ptr, const int* __restrict__ csr_src,
                                 const float* __restrict__ bias, float* __restrict__ out, int N){
  __shared__ int   sIdx[8][64];
  __shared__ float sP[8][64];
  const int lane = threadIdx.x & 63;
  const int wid  = threadIdx.x >> 6;
  const int n = blockIdx.x*8 + wid;
  if (n >= N) return;
  const int start = row_ptr[n], end = row_ptr[n+1];
  const float edn = ed[n];
  const int c0 = lane*2;
  float accx=0.f, accy=0.f, z=0.f;
  for (int t0 = start; t0 < end; t0 += 64){
    const int cnt = min(64, end - t0);
    if (lane < cnt){
      const int s = csr_src[t0 + lane];
      sIdx[wid][lane] = s;
      float p0 = es[s] + edn; p0 = (p0>=0.f)? p0 : NEG*p0; p0 = fminf(p0, 80.f);
      sP[wid][lane] = __expf(p0);
    }
    #pragma unroll 8
    for (int e = 0; e < cnt; e++){
      const int s = sIdx[wid][e];
      const float p = sP[wid][e];
      const float2 hv = *reinterpret_cast<const float2*>(h + (size_t)s*D + c0);
      z += p;
      accx = fmaf(p, hv.x, accx);
      accy = fmaf(p, hv.y, accy);
    }
  }
  const float inv = 1.f/(z + EPSV);
  const float ox = fmaf(accx, inv, bias[c0]), oy = fmaf(accy, inv, bias[c0+1]);
  *reinterpret_cast<float2*>(out + (size_t)n*D + c0) = make_float2(ox, oy);
}

extern "C" void kernel_launch(void* const* d_in, const int* in_sizes, int n_in,
                              void* d_out, int out_size, void* d_ws, size_t ws_size,
                              hipStream_t stream) {
  const float* x          = (const float*)d_in[0];
  const int*   ei         = (const int*)d_in[1];
  const float* Ws         = (const float*)d_in[2];
  const float* a_src      = (const float*)d_in[3];
  const float* a_dst      = (const float*)d_in[4];
  const float* bs         = (const float*)d_in[5];
  const float* W_last     = (const float*)d_in[6];
  const float* a_src_last = (const float*)d_in[7];
  const float* a_dst_last = (const float*)d_in[8];
  const float* b_last     = (const float*)d_in[9];

  const int N = in_sizes[0]/D;
  const int E = in_sizes[1]/2;
  const int L = in_sizes[2]/(D*D);   // 19 mid layers
  const int* esrc = ei;
  const int* edst = ei + E;

  // workspace layout (double-buffered h/es/ed; no x round-trip buffers needed)
  char* ws = (char*)d_ws;
  float* h0  = (float*)ws;  ws += (size_t)N*D*sizeof(float);
  float* h1  = (float*)ws;  ws += (size_t)N*D*sizeof(float);
  float* es0 = (float*)ws;  ws += (size_t)N*4*sizeof(float);
  float* es1 = (float*)ws;  ws += (size_t)N*4*sizeof(float);
  float* ed0 = (float*)ws;  ws += (size_t)N*4*sizeof(float);
  float* ed1 = (float*)ws;  ws += (size_t)N*4*sizeof(float);
  int* deg     = (int*)ws;  ws += (size_t)N*sizeof(int);
  int* row_ptr = (int*)ws;  ws += (size_t)(N+1)*sizeof(int);
  int* cursor  = (int*)ws;  ws += (size_t)N*sizeof(int);
  int* csr_src = (int*)ws;  ws += (size_t)(E+N)*sizeof(int);

  const int tot = E + N;
  hipMemsetAsync(deg, 0, (size_t)N*sizeof(int), stream);
  count_kernel<<<(tot+255)/256, 256, 0, stream>>>(edst, E, N, deg);
  scan_kernel<<<1, 1024, 0, stream>>>(deg, N, row_ptr, cursor);
  scatter_kernel<<<(tot+255)/256, 256, 0, stream>>>(esrc, edst, E, N, cursor, csr_src);

  const int gA = (N + 7)/8;

  // layer 0 linear
  linear0_kernel<<<gA, 512, 0, stream>>>(x, Ws, a_src, a_dst, N, h0, es0, ed0);

  const float *hc = h0, *esc = es0, *edc = ed0;
  float *hn = h1, *esn = es1, *edn = ed1;

  // fused aggregate(l) + linear(l+1), l = 0..L-2
  for (int l = 0; l < L-1; l++){
    fused_kernel<4><<<gA, 512, 0, stream>>>(hc, esc, edc, row_ptr, csr_src,
                                            bs + (size_t)l*D,
                                            Ws + (size_t)(l+1)*D*D, a_src + (size_t)(l+1)*D, a_dst + (size_t)(l+1)*D,
                                            N, hn, esn, edn);
    const float* tf;
    tf = hc;  hc = hn;  hn = (float*)tf;
    tf = esc; esc = esn; esn = (float*)tf;
    tf = edc; edc = edn; edn = (float*)tf;
  }

  // fused aggregate(L-1) + last linear (heads=1)
  fused_kernel<1><<<gA, 512, 0, stream>>>(hc, esc, edc, row_ptr, csr_src,
                                          bs + (size_t)(L-1)*D,
                                          W_last, a_src_last, a_dst_last,
                                          N, hn, esn, edn);
  {
    const float* tf;
    tf = hc;  hc = hn;  hn = (float*)tf;
    tf = esc; esc = esn; esn = (float*)tf;
    tf = edc; edc = edn; edn = (float*)tf;
  }

  // final aggregation (heads=1, no relu) -> d_out
  final_agg_kernel<<<gA, 512, 0, stream>>>(hc, esc, edc, row_ptr, csr_src, b_last, (float*)d_out, N);
}